// Round 12
// baseline (820.404 us; speedup 1.0000x reference)
//
#include <hip/hip_runtime.h>
#include <hip/hip_bf16.h>
#include <math.h>

#define D 256
#define EPS 1e-5f
#define SCAN_NB 256

typedef _Float16 f16;
typedef _Float16 f16x2 __attribute__((ext_vector_type(2)));
typedef _Float16 f16x4 __attribute__((ext_vector_type(4)));
typedef _Float16 f16x8 __attribute__((ext_vector_type(8)));
typedef float f32x4v __attribute__((ext_vector_type(4)));

// ---------------------------------------------------------------- CSR build
__global__ void k_count(const int* __restrict__ dst, int* __restrict__ cnt, int E) {
    int e = blockIdx.x * blockDim.x + threadIdx.x;
    if (e < E) atomicAdd(&cnt[dst[e]], 1);
}

__global__ void k_scan_part(const int* __restrict__ cnt, int* __restrict__ row_ptr,
                            int* __restrict__ partial, int N, int C) {
    __shared__ int sdata[256];
    int b = blockIdx.x, t = threadIdx.x;
    int base = b * C;
    int end = base + C; if (end > N) end = N;
    int running = 0;
    for (int ts = base; ts < end; ts += 256) {
        int idx = ts + t;
        int val = (idx < end) ? cnt[idx] : 0;
        sdata[t] = val;
        __syncthreads();
        for (int s = 1; s < 256; s <<= 1) {
            int v = (t >= s) ? sdata[t - s] : 0;
            __syncthreads();
            sdata[t] += v;
            __syncthreads();
        }
        if (idx < end) row_ptr[idx] = running + sdata[t] - val;
        running += sdata[255];
        __syncthreads();
    }
    if (t == 0) partial[b] = running;
}

__global__ void k_scan_off(int* __restrict__ partial) {
    __shared__ int sdata[256];
    int t = threadIdx.x;
    int val = partial[t];
    sdata[t] = val;
    __syncthreads();
    for (int s = 1; s < 256; s <<= 1) {
        int v = (t >= s) ? sdata[t - s] : 0;
        __syncthreads();
        sdata[t] += v;
        __syncthreads();
    }
    partial[t] = sdata[t] - val;
}

__global__ void k_scan_add(int* __restrict__ row_ptr, int* __restrict__ cursor,
                           const int* __restrict__ partial, const int* __restrict__ cnt,
                           float* __restrict__ dinv, int N, int C, int E) {
    int i = blockIdx.x * 256 + threadIdx.x;
    if (i < N) {
        int v = row_ptr[i] + partial[i / C];
        row_ptr[i] = v;
        cursor[i]  = v;
        dinv[i] = rsqrtf(1.0f + (float)cnt[i]);
    }
    if (i == N) row_ptr[N] = E;
}

// packed edge record: {src, coef bits}
__global__ void k_fill(const int* __restrict__ src, const int* __restrict__ dst,
                       const float* __restrict__ dinv, int* __restrict__ cursor,
                       int2* __restrict__ ecp, int E) {
    int e = blockIdx.x * blockDim.x + threadIdx.x;
    if (e >= E) return;
    int s = src[e], t = dst[e];
    int slot = atomicAdd(&cursor[t], 1);
    ecp[slot] = make_int2(s, __float_as_int(dinv[s] * dinv[t]));
}

// ---------------------------------------------------------------- casts / weight prep
__global__ void k_cast(const float* __restrict__ in, f16* __restrict__ o, int n4) {
    int i = blockIdx.x * 256 + threadIdx.x;
    if (i >= n4) return;
    float4 v = ((const float4*)in)[i];
    f16x4 h = {(f16)v.x, (f16)v.y, (f16)v.z, (f16)v.w};
    ((f16x4*)o)[i] = h;
}

// Wt[d][k] = (f16) W[k][d]; block 0 zeroes BN-stat accumulators.
__global__ void k_prep_w(const float* __restrict__ W, f16* __restrict__ Wt, int K,
                         float* __restrict__ sums, float* __restrict__ sumsq) {
    int idx = blockIdx.x * 256 + threadIdx.x;
    if (blockIdx.x == 0) {
        sums[threadIdx.x]  = 0.f;
        sumsq[threadIdx.x] = 0.f;
    }
    if (idx >= K * 256) return;
    int k = idx >> 8, d = idx & 255;
    Wt[(size_t)d * K + k] = (f16)W[idx];
}

// ---------------------------------------------------------------- MFMA GEMM (128x128, 2x2 waves, 4x4 MFMA each)
#define KSTEP 32
#define ATS 40
__global__ __launch_bounds__(256)
void k_gemm(const f16* __restrict__ A, const f16* __restrict__ Wt,
            f16* __restrict__ outh, int N, int K,
            float* __restrict__ sums, float* __restrict__ sumsq) {
    __shared__ __align__(16) f16 As[128 * ATS];
    __shared__ __align__(16) f16 Bs[128 * ATS];
    const int r0 = blockIdx.x * 128;
    const int c0 = blockIdx.y * 128;
    const int t = threadIdx.x;
    const int lane = t & 63, wave = t >> 6;
    const int wr = wave >> 1, wc = wave & 1;
    const int quad = lane >> 4, m = lane & 15;

    f32x4v acc[4][4];
#pragma unroll
    for (int i = 0; i < 4; ++i)
#pragma unroll
        for (int j = 0; j < 4; ++j) acc[i][j] = {0.f, 0.f, 0.f, 0.f};

    const int sr = t >> 1;
    const int sc8 = (t & 1) * 16;

    for (int k0 = 0; k0 < K; k0 += KSTEP) {
        int gr = r0 + sr;
        uint4 a0 = make_uint4(0u,0u,0u,0u), a1 = make_uint4(0u,0u,0u,0u);
        if (gr < N) {
            const f16* ap = A + (size_t)gr * K + k0 + sc8;
            a0 = *(const uint4*)ap;
            a1 = *(const uint4*)(ap + 8);
        }
        *(uint4*)(As + sr * ATS + sc8)     = a0;
        *(uint4*)(As + sr * ATS + sc8 + 8) = a1;
        const f16* bp = Wt + (size_t)(c0 + sr) * K + k0 + sc8;
        *(uint4*)(Bs + sr * ATS + sc8)     = *(const uint4*)bp;
        *(uint4*)(Bs + sr * ATS + sc8 + 8) = *(const uint4*)(bp + 8);
        __syncthreads();

        f16x8 af[4], bf[4];
#pragma unroll
        for (int i = 0; i < 4; ++i)
            af[i] = *(const f16x8*)(As + (wr * 64 + i * 16 + m) * ATS + quad * 8);
#pragma unroll
        for (int j = 0; j < 4; ++j)
            bf[j] = *(const f16x8*)(Bs + (wc * 64 + j * 16 + m) * ATS + quad * 8);
#pragma unroll
        for (int i = 0; i < 4; ++i)
#pragma unroll
            for (int j = 0; j < 4; ++j)
                acc[i][j] = __builtin_amdgcn_mfma_f32_16x16x32_f16(af[i], bf[j], acc[i][j], 0, 0, 0);
        __syncthreads();
    }

#pragma unroll
    for (int i = 0; i < 4; ++i) {
#pragma unroll
        for (int r = 0; r < 4; ++r) {
            int row = r0 + wr * 64 + i * 16 + quad * 4 + r;
            if (row < N) {
#pragma unroll
                for (int j = 0; j < 4; ++j) {
                    int colm = c0 + wc * 64 + j * 16 + m;
                    outh[(size_t)row * D + colm] = (f16)acc[i][j][r];
                }
            }
        }
    }

    if (sums) {
        __shared__ float cs[128], css[128];
        if (t < 128) { cs[t] = 0.f; css[t] = 0.f; }
        __syncthreads();
#pragma unroll
        for (int j = 0; j < 4; ++j) {
            int f = wc * 64 + j * 16 + m;
            float s = 0.f, q = 0.f;
#pragma unroll
            for (int i = 0; i < 4; ++i)
#pragma unroll
                for (int r = 0; r < 4; ++r) {
                    float v = acc[i][j][r];
                    s += v; q += v * v;
                }
            atomicAdd(&cs[f], s);
            atomicAdd(&css[f], q);
        }
        __syncthreads();
        if (t < 128) {
            atomicAdd(&sums[c0 + t], cs[t]);
            atomicAdd(&sumsq[c0 + t], css[t]);
        }
    }
}

// ---------------------------------------------------------------- chunked gather
// 32-feature chunks: chunk = blockIdx.x % NCHUNK (round-robin dispatch => chunk ~ XCD),
// so the per-XCD L2 row working set is N*64B = 3.2 MB (fits 4 MB L2).
// 16 lanes per node (f16x2/lane, node-slice = one 64B cache line), 4 nodes/wave,
// predicated x8 edge unroll -> 32 independent line-fills in flight per wave.
template<int KD, int NCHUNK>
__global__ __launch_bounds__(256)
void k_gather_chunk(const int* __restrict__ row_ptr, const int2* __restrict__ ecp,
                    const f16* __restrict__ hw, const float* __restrict__ dinv,
                    f16* __restrict__ out, float* __restrict__ sums,
                    float* __restrict__ sumsq, int N) {
    const int t = threadIdx.x;
    const int lane = t & 63, wave = t >> 6;
    const int q = lane >> 4, m = lane & 15;
    const int c = blockIdx.x % NCHUNK;
    const int bstripe = blockIdx.x / NCHUNK;
    const int nstripes = gridDim.x / NCHUNK;
    const int fb = c * 32 + m * 2;               // this lane's feature pair

    __shared__ float rs[32], rss[32];
    if (sums) {
        if (t < 32) { rs[t] = 0.f; rss[t] = 0.f; }
        __syncthreads();
    }

    float sx = 0.f, sy = 0.f, qx = 0.f, qy = 0.f;

    int slot   = (bstripe * 4 + wave) * 4 + q;
    int stride = nstripes * 16;
    for (int i = slot; i < N; i += stride) {
        int lo = row_ptr[i], hi = row_ptr[i + 1];
        float dd = dinv[i]; dd *= dd;
        f16x2 hv = *(const f16x2*)(hw + (size_t)i * KD + fb);
        float ax = (float)hv[0] * dd;
        float ay = (float)hv[1] * dd;

        for (int e = lo; e < hi; e += 8) {
            int nd[8]; float cf[8];
#pragma unroll
            for (int j = 0; j < 8; ++j) {
                int ej = e + j;
                int2 ec = ecp[(ej < hi) ? ej : lo];
                nd[j] = ec.x;
                cf[j] = (ej < hi) ? __int_as_float(ec.y) : 0.f;
            }
            f16x2 r[8];
#pragma unroll
            for (int j = 0; j < 8; ++j)
                r[j] = *(const f16x2*)(hw + (size_t)nd[j] * KD + fb);
#pragma unroll
            for (int j = 0; j < 8; ++j) {
                ax = fmaf((float)r[j][0], cf[j], ax);
                ay = fmaf((float)r[j][1], cf[j], ay);
            }
        }

        f16x2 o = {(f16)ax, (f16)ay};
        *(f16x2*)(out + (size_t)i * KD + fb) = o;
        sx += ax; sy += ay;
        qx += ax * ax; qy += ay * ay;
    }

    if (sums) {
        atomicAdd(&rs[m * 2], sx);      atomicAdd(&rs[m * 2 + 1], sy);
        atomicAdd(&rss[m * 2], qx);     atomicAdd(&rss[m * 2 + 1], qy);
        __syncthreads();
        if (t < 32) {
            atomicAdd(&sums[c * 32 + t], rs[t]);
            atomicAdd(&sumsq[c * 32 + t], rss[t]);
        }
    }
}

// ---------------------------------------------------------------- BN + tanh (f16 in, f16 out)
__global__ void k_bn_tanh_h(const f16* __restrict__ h, const float* __restrict__ sums,
                            const float* __restrict__ sumsq, const float* __restrict__ g,
                            const float* __restrict__ be, float Ninv,
                            f16* __restrict__ hh, int n4) {
    int i = blockIdx.x * blockDim.x + threadIdx.x;
    if (i >= n4) return;
    int d = (i & 63) * 4;
    f16x4 v = ((const f16x4*)h)[i];
    f16x4 o;
#pragma unroll
    for (int j = 0; j < 4; ++j) {
        float mu  = sums[d + j] * Ninv;
        float var = sumsq[d + j] * Ninv - mu * mu;
        float s   = g[d + j] * rsqrtf(var + EPS);
        float sh  = be[d + j] - mu * s;
        o[j] = (f16)tanhf(fmaf((float)v[j], s, sh));
    }
    ((f16x4*)hh)[i] = o;
}

// ---------------------------------------------------------------- pool with fused last-layer BN + tanh
__device__ __forceinline__ int lb(const int* __restrict__ a, int n, int v) {
    int lo = 0, hi = n;
    while (lo < hi) {
        int mid = (lo + hi) >> 1;
        if (a[mid] < v) lo = mid + 1; else hi = mid;
    }
    return lo;
}

__global__ void k_pool(const f16* __restrict__ agg, const float* __restrict__ sums,
                       const float* __restrict__ sumsq, const float* __restrict__ gg,
                       const float* __restrict__ be, float Ninv,
                       const int* __restrict__ batch,
                       const float* __restrict__ Wout, const float* __restrict__ bout,
                       float* __restrict__ out, float* __restrict__ hidden, int N) {
    int g = blockIdx.x;
    int d = threadIdx.x;
    float mu  = sums[d] * Ninv;
    float var = sumsq[d] * Ninv - mu * mu;
    float sc  = gg[d] * rsqrtf(var + EPS);
    float sh  = be[d] - mu * sc;

    int lo = lb(batch, N, g);
    int hi = lb(batch, N, g + 1);
    float mx = -INFINITY, sm = 0.0f;
    for (int i = lo; i < hi; ++i) {
        float v = tanhf(fmaf((float)agg[(size_t)i * D + d], sc, sh));
        mx = fmaxf(mx, v);
        sm += v;
    }
    float mean = sm / (float)(hi - lo);
    hidden[(size_t)g * (2 * D) + d] = mx;
    hidden[(size_t)g * (2 * D) + D + d] = mean;

    float p = mx * Wout[d] + mean * Wout[D + d];
    __shared__ float red[256];
    red[d] = p;
    __syncthreads();
    for (int s = 128; s > 0; s >>= 1) {
        if (d < s) red[d] += red[d + s];
        __syncthreads();
    }
    if (d == 0) out[g] = red[0] + bout[0];
}

// ----------------------------------------------------------------
extern "C" void kernel_launch(void* const* d_in, const int* in_sizes, int n_in,
                              void* d_out, int out_size, void* d_ws, size_t ws_size,
                              hipStream_t stream) {
    const float* x          = (const float*)d_in[0];
    const int*   edge_index = (const int*)d_in[1];
    const int*   batch      = (const int*)d_in[2];
    const float* Wl[4] = {(const float*)d_in[4], (const float*)d_in[6],
                          (const float*)d_in[8], (const float*)d_in[10]};
    const float* gl[4]  = {(const float*)d_in[12], (const float*)d_in[14],
                           (const float*)d_in[16], (const float*)d_in[18]};
    const float* bel[4] = {(const float*)d_in[13], (const float*)d_in[15],
                           (const float*)d_in[17], (const float*)d_in[19]};
    const float* Wout = (const float*)d_in[20];
    const float* bout = (const float*)d_in[21];

    const int N = in_sizes[0] / 64;       // 50000
    const int E = in_sizes[1] / 2;        // 800000
    const int B = out_size / (1 + 2 * D); // 1000

    const int* srcv = edge_index;
    const int* dstv = edge_index + E;

    // workspace carve-up
    f16*   hw_h    = (f16*)d_ws;                // [N,D] GEMM out
    f16*   hh      = hw_h + (size_t)N * D;      // [N,D] activations
    f16*   agg_h   = hh + (size_t)N * D;        // [N,D] gather out
    f16*   xh      = agg_h + (size_t)N * D;     // [N,64]
    f16*   aggx    = xh + (size_t)N * 64;       // [N,64]
    f16*   Wt      = aggx + (size_t)N * 64;     // [256,256]
    float* dinv    = (float*)(Wt + 256 * 256);  // [N]
    float* sums    = dinv + N;                  // [D]
    float* sumsq   = sums + D;                  // [D]
    int2*  ecp     = (int2*)(sumsq + D);        // [E] packed {col, coef}
    int*   cnt     = (int*)(ecp + E);           // [N]
    int*   row_ptr = cnt + N;                   // [N+1]
    int*   cursor  = row_ptr + N + 1;           // [N]
    int*   partial = cursor + N;                // [SCAN_NB]

    float* out_p    = (float*)d_out;            // [B]
    float* hidden_p = out_p + B;                // [B, 512]

    // ---- CSR build
    hipMemsetAsync(cnt, 0, (size_t)N * sizeof(int), stream);
    k_count<<<(E + 255) / 256, 256, 0, stream>>>(dstv, cnt, E);
    const int C = (N + SCAN_NB - 1) / SCAN_NB;
    k_scan_part<<<SCAN_NB, 256, 0, stream>>>(cnt, row_ptr, partial, N, C);
    k_scan_off<<<1, 256, 0, stream>>>(partial);
    k_scan_add<<<(N + 1 + 255) / 256, 256, 0, stream>>>(row_ptr, cursor, partial,
                                                        cnt, dinv, N, C, E);
    k_fill<<<(E + 255) / 256, 256, 0, stream>>>(srcv, dstv, dinv, cursor, ecp, E);

    // x -> f16
    k_cast<<<(N * 64 / 4 + 255) / 256, 256, 0, stream>>>(x, xh, N * 64 / 4);

    const dim3 gemm_grid((N + 127) / 128, 2);
    const int nd4 = N * D / 4;

    // ---- layer 0: chunked agg(X) -> GEMM(+stats) -> BN+tanh
    k_gather_chunk<64, 2><<<2048, 256, 0, stream>>>(row_ptr, ecp, xh, dinv, aggx,
                                                    nullptr, nullptr, N);
    k_prep_w<<<64, 256, 0, stream>>>(Wl[0], Wt, 64, sums, sumsq);
    k_gemm<<<gemm_grid, 256, 0, stream>>>(aggx, Wt, hw_h, N, 64, sums, sumsq);
    k_bn_tanh_h<<<(nd4 + 255) / 256, 256, 0, stream>>>(
        hw_h, sums, sumsq, gl[0], bel[0], 1.0f / (float)N, hh, nd4);

    // ---- layers 1-3: GEMM -> chunked gather(+stats) -> BN+tanh (layer 3 BN fused into pool)
    for (int l = 1; l < 4; ++l) {
        k_prep_w<<<256, 256, 0, stream>>>(Wl[l], Wt, 256, sums, sumsq);
        k_gemm<<<gemm_grid, 256, 0, stream>>>(hh, Wt, hw_h, N, 256, nullptr, nullptr);
        k_gather_chunk<256, 8><<<2048, 256, 0, stream>>>(row_ptr, ecp, hw_h, dinv,
                                                         agg_h, sums, sumsq, N);
        if (l < 3) {
            k_bn_tanh_h<<<(nd4 + 255) / 256, 256, 0, stream>>>(
                agg_h, sums, sumsq, gl[l], bel[l], 1.0f / (float)N, hh, nd4);
        }
    }

    k_pool<<<B, 256, 0, stream>>>(agg_h, sums, sumsq, gl[3], bel[3], 1.0f / (float)N,
                                  batch, Wout, bout, out_p, hidden_p, N);
}

// Round 13
// 747.062 us; speedup vs baseline: 1.0982x; 1.0982x over previous
//
#include <hip/hip_runtime.h>
#include <hip/hip_bf16.h>
#include <math.h>

#define D 256
#define EPS 1e-5f
#define SCAN_NB 256

typedef _Float16 f16;
typedef _Float16 f16x2 __attribute__((ext_vector_type(2)));
typedef _Float16 f16x4 __attribute__((ext_vector_type(4)));
typedef _Float16 f16x8 __attribute__((ext_vector_type(8)));
typedef float f32x4v __attribute__((ext_vector_type(4)));

// ---------------------------------------------------------------- CSR build
__global__ void k_count(const int* __restrict__ dst, int* __restrict__ cnt, int E) {
    int e = blockIdx.x * blockDim.x + threadIdx.x;
    if (e < E) atomicAdd(&cnt[dst[e]], 1);
}

__global__ void k_scan_part(const int* __restrict__ cnt, int* __restrict__ row_ptr,
                            int* __restrict__ partial, int N, int C) {
    __shared__ int sdata[256];
    int b = blockIdx.x, t = threadIdx.x;
    int base = b * C;
    int end = base + C; if (end > N) end = N;
    int running = 0;
    for (int ts = base; ts < end; ts += 256) {
        int idx = ts + t;
        int val = (idx < end) ? cnt[idx] : 0;
        sdata[t] = val;
        __syncthreads();
        for (int s = 1; s < 256; s <<= 1) {
            int v = (t >= s) ? sdata[t - s] : 0;
            __syncthreads();
            sdata[t] += v;
            __syncthreads();
        }
        if (idx < end) row_ptr[idx] = running + sdata[t] - val;
        running += sdata[255];
        __syncthreads();
    }
    if (t == 0) partial[b] = running;
}

__global__ void k_scan_off(int* __restrict__ partial) {
    __shared__ int sdata[256];
    int t = threadIdx.x;
    int val = partial[t];
    sdata[t] = val;
    __syncthreads();
    for (int s = 1; s < 256; s <<= 1) {
        int v = (t >= s) ? sdata[t - s] : 0;
        __syncthreads();
        sdata[t] += v;
        __syncthreads();
    }
    partial[t] = sdata[t] - val;
}

__global__ void k_scan_add(int* __restrict__ row_ptr, int* __restrict__ cursor,
                           const int* __restrict__ partial, const int* __restrict__ cnt,
                           float* __restrict__ dinv, int N, int C, int E) {
    int i = blockIdx.x * 256 + threadIdx.x;
    if (i < N) {
        int v = row_ptr[i] + partial[i / C];
        row_ptr[i] = v;
        cursor[i]  = v;
        dinv[i] = rsqrtf(1.0f + (float)cnt[i]);
    }
    if (i == N) row_ptr[N] = E;
}

// packed edge record: {src, coef bits}
__global__ void k_fill(const int* __restrict__ src, const int* __restrict__ dst,
                       const float* __restrict__ dinv, int* __restrict__ cursor,
                       int2* __restrict__ ecp, int E) {
    int e = blockIdx.x * blockDim.x + threadIdx.x;
    if (e >= E) return;
    int s = src[e], t = dst[e];
    int slot = atomicAdd(&cursor[t], 1);
    ecp[slot] = make_int2(s, __float_as_int(dinv[s] * dinv[t]));
}

// ---------------------------------------------------------------- cast (+ zero layer-0 BN stats)
__global__ void k_cast(const float* __restrict__ in, f16* __restrict__ o, int n4,
                       float* __restrict__ sums, float* __restrict__ sumsq) {
    int i = blockIdx.x * 256 + threadIdx.x;
    if (blockIdx.x == 0) {
        sums[threadIdx.x]  = 0.f;
        sumsq[threadIdx.x] = 0.f;
    }
    if (i >= n4) return;
    float4 v = ((const float4*)in)[i];
    f16x4 h = {(f16)v.x, (f16)v.y, (f16)v.z, (f16)v.w};
    ((f16x4*)o)[i] = h;
}

// ---------------------------------------------------------------- all-layer weight prep (one dispatch)
// Wt_l[d][k] = (f16) W_l[k][d]; L0: K=64, L1-3: K=256.
__global__ void k_prep_w_all(const float* __restrict__ W0, const float* __restrict__ W1,
                             const float* __restrict__ W2, const float* __restrict__ W3,
                             f16* __restrict__ T0, f16* __restrict__ T1,
                             f16* __restrict__ T2, f16* __restrict__ T3) {
    int idx = blockIdx.x * 256 + threadIdx.x;
    if (idx < 16384) {                       // L0: 64x256
        int k = idx >> 8, d = idx & 255;
        T0[(size_t)d * 64 + k] = (f16)W0[idx];
        return;
    }
    idx -= 16384;
    const float* W; f16* T;
    if (idx < 65536)      { W = W1; T = T1; }
    else if (idx < 131072){ W = W2; T = T2; idx -= 65536; }
    else                  { W = W3; T = T3; idx -= 131072; }
    int k = idx >> 8, d = idx & 255;
    T[(size_t)d * 256 + k] = (f16)W[idx];
}

// ---------------------------------------------------------------- MFMA GEMM (128x128, 2x2 waves, 4x4 MFMA)
// zs/zq: if non-null, redundantly zero the BN-stat accumulators (consumed by the NEXT kernel).
// sums/sumsq: if non-null, accumulate column stats (layer-0 epilogue).
#define KSTEP 32
#define ATS 40
__global__ __launch_bounds__(256)
void k_gemm(const f16* __restrict__ A, const f16* __restrict__ Wt,
            f16* __restrict__ outh, int N, int K,
            float* __restrict__ sums, float* __restrict__ sumsq,
            float* __restrict__ zs, float* __restrict__ zq) {
    __shared__ __align__(16) f16 As[128 * ATS];
    __shared__ __align__(16) f16 Bs[128 * ATS];
    const int r0 = blockIdx.x * 128;
    const int c0 = blockIdx.y * 128;
    const int t = threadIdx.x;
    const int lane = t & 63, wave = t >> 6;
    const int wr = wave >> 1, wc = wave & 1;
    const int quad = lane >> 4, m = lane & 15;

    if (zs) { zs[t] = 0.f; zq[t] = 0.f; }   // all blocks store 0 — benign race

    f32x4v acc[4][4];
#pragma unroll
    for (int i = 0; i < 4; ++i)
#pragma unroll
        for (int j = 0; j < 4; ++j) acc[i][j] = {0.f, 0.f, 0.f, 0.f};

    const int sr = t >> 1;
    const int sc8 = (t & 1) * 16;

    for (int k0 = 0; k0 < K; k0 += KSTEP) {
        int gr = r0 + sr;
        uint4 a0 = make_uint4(0u,0u,0u,0u), a1 = make_uint4(0u,0u,0u,0u);
        if (gr < N) {
            const f16* ap = A + (size_t)gr * K + k0 + sc8;
            a0 = *(const uint4*)ap;
            a1 = *(const uint4*)(ap + 8);
        }
        *(uint4*)(As + sr * ATS + sc8)     = a0;
        *(uint4*)(As + sr * ATS + sc8 + 8) = a1;
        const f16* bp = Wt + (size_t)(c0 + sr) * K + k0 + sc8;
        *(uint4*)(Bs + sr * ATS + sc8)     = *(const uint4*)bp;
        *(uint4*)(Bs + sr * ATS + sc8 + 8) = *(const uint4*)(bp + 8);
        __syncthreads();

        f16x8 af[4], bf[4];
#pragma unroll
        for (int i = 0; i < 4; ++i)
            af[i] = *(const f16x8*)(As + (wr * 64 + i * 16 + m) * ATS + quad * 8);
#pragma unroll
        for (int j = 0; j < 4; ++j)
            bf[j] = *(const f16x8*)(Bs + (wc * 64 + j * 16 + m) * ATS + quad * 8);
#pragma unroll
        for (int i = 0; i < 4; ++i)
#pragma unroll
            for (int j = 0; j < 4; ++j)
                acc[i][j] = __builtin_amdgcn_mfma_f32_16x16x32_f16(af[i], bf[j], acc[i][j], 0, 0, 0);
        __syncthreads();
    }

#pragma unroll
    for (int i = 0; i < 4; ++i) {
#pragma unroll
        for (int r = 0; r < 4; ++r) {
            int row = r0 + wr * 64 + i * 16 + quad * 4 + r;
            if (row < N) {
#pragma unroll
                for (int j = 0; j < 4; ++j) {
                    int colm = c0 + wc * 64 + j * 16 + m;
                    outh[(size_t)row * D + colm] = (f16)acc[i][j][r];
                }
            }
        }
    }

    if (sums) {
        __shared__ float cs[128], css[128];
        if (t < 128) { cs[t] = 0.f; css[t] = 0.f; }
        __syncthreads();
#pragma unroll
        for (int j = 0; j < 4; ++j) {
            int f = wc * 64 + j * 16 + m;
            float s = 0.f, q = 0.f;
#pragma unroll
            for (int i = 0; i < 4; ++i)
#pragma unroll
                for (int r = 0; r < 4; ++r) {
                    float v = acc[i][j][r];
                    s += v; q += v * v;
                }
            atomicAdd(&cs[f], s);
            atomicAdd(&css[f], q);
        }
        __syncthreads();
        if (t < 128) {
            atomicAdd(&sums[c0 + t], cs[t]);
            atomicAdd(&sumsq[c0 + t], css[t]);
        }
    }
}

// ---------------------------------------------------------------- gather, 256-dim rows (layers 1-3)
// wave-per-node, f16x4/lane, predicated x8 unroll (round-8 body), packed int2 edges.
__global__ __launch_bounds__(256)
void k_gather(const int* __restrict__ row_ptr, const int2* __restrict__ ecp,
              const f16* __restrict__ hw, const float* __restrict__ dinv,
              f16* __restrict__ out, float* __restrict__ sums,
              float* __restrict__ sumsq, int N) {
    const int lane = threadIdx.x & 63;
    const int wave = threadIdx.x >> 6;
    const f16x4* __restrict__ hw4 = (const f16x4*)hw;
    f16x4* __restrict__ out4 = (f16x4*)out;

    float4 s4  = make_float4(0.f, 0.f, 0.f, 0.f);
    float4 ss4 = make_float4(0.f, 0.f, 0.f, 0.f);

    int wslot  = blockIdx.x * 4 + wave;
    int wtotal = gridDim.x * 4;
    for (int i = wslot; i < N; i += wtotal) {
        int lo = row_ptr[i];
        int hi = row_ptr[i + 1];
        float dd = dinv[i]; dd *= dd;
        f16x4 hv = hw4[(size_t)i * 64 + lane];
        float4 acc;
        acc.x = (float)hv[0] * dd;
        acc.y = (float)hv[1] * dd;
        acc.z = (float)hv[2] * dd;
        acc.w = (float)hv[3] * dd;

        for (int e = lo; e < hi; e += 8) {
            int nd[8]; float cf[8];
#pragma unroll
            for (int j = 0; j < 8; ++j) {
                int ej = e + j;
                int2 ec = ecp[(ej < hi) ? ej : lo];
                nd[j] = ec.x;
                cf[j] = (ej < hi) ? __int_as_float(ec.y) : 0.f;
            }
            f16x4 r[8];
#pragma unroll
            for (int j = 0; j < 8; ++j) r[j] = hw4[(size_t)nd[j] * 64 + lane];
#pragma unroll
            for (int j = 0; j < 8; ++j) {
                acc.x = fmaf((float)r[j][0], cf[j], acc.x);
                acc.y = fmaf((float)r[j][1], cf[j], acc.y);
                acc.z = fmaf((float)r[j][2], cf[j], acc.z);
                acc.w = fmaf((float)r[j][3], cf[j], acc.w);
            }
        }

        f16x4 o = {(f16)acc.x, (f16)acc.y, (f16)acc.z, (f16)acc.w};
        out4[(size_t)i * 64 + lane] = o;
        s4.x += acc.x; s4.y += acc.y; s4.z += acc.z; s4.w += acc.w;
        ss4.x += acc.x * acc.x; ss4.y += acc.y * acc.y;
        ss4.z += acc.z * acc.z; ss4.w += acc.w * acc.w;
    }

    __shared__ float rs[4][256];
    __shared__ float rss[4][256];
    int f = lane * 4;
    rs[wave][f + 0] = s4.x;  rs[wave][f + 1] = s4.y;
    rs[wave][f + 2] = s4.z;  rs[wave][f + 3] = s4.w;
    rss[wave][f + 0] = ss4.x; rss[wave][f + 1] = ss4.y;
    rss[wave][f + 2] = ss4.z; rss[wave][f + 3] = ss4.w;
    __syncthreads();
    int t = threadIdx.x;
    float rsum  = rs[0][t] + rs[1][t] + rs[2][t] + rs[3][t];
    float rsum2 = rss[0][t] + rss[1][t] + rss[2][t] + rss[3][t];
    atomicAdd(&sums[t], rsum);
    atomicAdd(&sumsq[t], rsum2);
}

// ---------------------------------------------------------------- gather64: quad-node per wave (layer 0 on X)
__global__ __launch_bounds__(256)
void k_gather64(const int* __restrict__ row_ptr, const int2* __restrict__ ecp,
                const f16* __restrict__ xh, const float* __restrict__ dinv,
                f16* __restrict__ aggx, int N) {
    const int lane = threadIdx.x & 63;
    const int wave = threadIdx.x >> 6;
    const int q = lane >> 4, m = lane & 15;
    const f16x4* __restrict__ x4 = (const f16x4*)xh;
    f16x4* __restrict__ o4 = (f16x4*)aggx;

    int slot   = blockIdx.x * 4 + wave;
    int stride = gridDim.x * 4;
    for (int i0 = slot * 4; i0 < N; i0 += stride * 4) {
        int i = i0 + q;
        bool act = i < N;
        int lo = act ? row_ptr[i] : 0;
        int hi = act ? row_ptr[i + 1] : 0;
        float dd = act ? dinv[i] : 0.f; dd *= dd;
        f16x4 hv = act ? x4[(size_t)i * 16 + m] : (f16x4){0,0,0,0};
        float4 acc;
        acc.x = (float)hv[0]*dd; acc.y = (float)hv[1]*dd;
        acc.z = (float)hv[2]*dd; acc.w = (float)hv[3]*dd;

        for (int e = lo; e < hi; e += 8) {
            int nd[8]; float cf[8];
#pragma unroll
            for (int j = 0; j < 8; ++j) {
                int ej = e + j;
                int2 ec = ecp[(ej < hi) ? ej : lo];
                nd[j] = ec.x;
                cf[j] = (ej < hi) ? __int_as_float(ec.y) : 0.f;
            }
            f16x4 r[8];
#pragma unroll
            for (int j = 0; j < 8; ++j) r[j] = x4[(size_t)nd[j] * 16 + m];
#pragma unroll
            for (int j = 0; j < 8; ++j) {
                acc.x = fmaf((float)r[j][0], cf[j], acc.x);
                acc.y = fmaf((float)r[j][1], cf[j], acc.y);
                acc.z = fmaf((float)r[j][2], cf[j], acc.z);
                acc.w = fmaf((float)r[j][3], cf[j], acc.w);
            }
        }
        if (act) {
            f16x4 o = {(f16)acc.x, (f16)acc.y, (f16)acc.z, (f16)acc.w};
            o4[(size_t)i * 16 + m] = o;
        }
    }
}

// ---------------------------------------------------------------- BN + tanh (f16 in, f16 out)
__global__ void k_bn_tanh_h(const f16* __restrict__ h, const float* __restrict__ sums,
                            const float* __restrict__ sumsq, const float* __restrict__ g,
                            const float* __restrict__ be, float Ninv,
                            f16* __restrict__ hh, int n4) {
    int i = blockIdx.x * blockDim.x + threadIdx.x;
    if (i >= n4) return;
    int d = (i & 63) * 4;
    f16x4 v = ((const f16x4*)h)[i];
    f16x4 o;
#pragma unroll
    for (int j = 0; j < 4; ++j) {
        float mu  = sums[d + j] * Ninv;
        float var = sumsq[d + j] * Ninv - mu * mu;
        float s   = g[d + j] * rsqrtf(var + EPS);
        float sh  = be[d + j] - mu * s;
        o[j] = (f16)tanhf(fmaf((float)v[j], s, sh));
    }
    ((f16x4*)hh)[i] = o;
}

// ---------------------------------------------------------------- pool with fused last-layer BN + tanh
__device__ __forceinline__ int lb(const int* __restrict__ a, int n, int v) {
    int lo = 0, hi = n;
    while (lo < hi) {
        int mid = (lo + hi) >> 1;
        if (a[mid] < v) lo = mid + 1; else hi = mid;
    }
    return lo;
}

__global__ void k_pool(const f16* __restrict__ agg, const float* __restrict__ sums,
                       const float* __restrict__ sumsq, const float* __restrict__ gg,
                       const float* __restrict__ be, float Ninv,
                       const int* __restrict__ batch,
                       const float* __restrict__ Wout, const float* __restrict__ bout,
                       float* __restrict__ out, float* __restrict__ hidden, int N) {
    int g = blockIdx.x;
    int d = threadIdx.x;
    float mu  = sums[d] * Ninv;
    float var = sumsq[d] * Ninv - mu * mu;
    float sc  = gg[d] * rsqrtf(var + EPS);
    float sh  = be[d] - mu * sc;

    int lo = lb(batch, N, g);
    int hi = lb(batch, N, g + 1);
    float mx = -INFINITY, sm = 0.0f;
    for (int i = lo; i < hi; ++i) {
        float v = tanhf(fmaf((float)agg[(size_t)i * D + d], sc, sh));
        mx = fmaxf(mx, v);
        sm += v;
    }
    float mean = sm / (float)(hi - lo);
    hidden[(size_t)g * (2 * D) + d] = mx;
    hidden[(size_t)g * (2 * D) + D + d] = mean;

    float p = mx * Wout[d] + mean * Wout[D + d];
    __shared__ float red[256];
    red[d] = p;
    __syncthreads();
    for (int s = 128; s > 0; s >>= 1) {
        if (d < s) red[d] += red[d + s];
        __syncthreads();
    }
    if (d == 0) out[g] = red[0] + bout[0];
}

// ----------------------------------------------------------------
extern "C" void kernel_launch(void* const* d_in, const int* in_sizes, int n_in,
                              void* d_out, int out_size, void* d_ws, size_t ws_size,
                              hipStream_t stream) {
    const float* x          = (const float*)d_in[0];
    const int*   edge_index = (const int*)d_in[1];
    const int*   batch      = (const int*)d_in[2];
    const float* Wl[4] = {(const float*)d_in[4], (const float*)d_in[6],
                          (const float*)d_in[8], (const float*)d_in[10]};
    const float* gl[4]  = {(const float*)d_in[12], (const float*)d_in[14],
                           (const float*)d_in[16], (const float*)d_in[18]};
    const float* bel[4] = {(const float*)d_in[13], (const float*)d_in[15],
                           (const float*)d_in[17], (const float*)d_in[19]};
    const float* Wout = (const float*)d_in[20];
    const float* bout = (const float*)d_in[21];

    const int N = in_sizes[0] / 64;       // 50000
    const int E = in_sizes[1] / 2;        // 800000
    const int B = out_size / (1 + 2 * D); // 1000

    const int* srcv = edge_index;
    const int* dstv = edge_index + E;

    // workspace carve-up
    f16*   hw_h    = (f16*)d_ws;                // [N,D] GEMM out
    f16*   hh      = hw_h + (size_t)N * D;      // [N,D] activations
    f16*   agg_h   = hh + (size_t)N * D;        // [N,D] gather out
    f16*   xh      = agg_h + (size_t)N * D;     // [N,64]
    f16*   aggx    = xh + (size_t)N * 64;       // [N,64]
    f16*   Wt0     = aggx + (size_t)N * 64;     // [256,64]
    f16*   Wt1     = Wt0 + 256 * 64;            // [256,256] x3
    f16*   Wt2     = Wt1 + 256 * 256;
    f16*   Wt3     = Wt2 + 256 * 256;
    float* dinv    = (float*)(Wt3 + 256 * 256); // [N]
    float* sums    = dinv + N;                  // [D]
    float* sumsq   = sums + D;                  // [D]
    int2*  ecp     = (int2*)(sumsq + D);        // [E]
    int*   cnt     = (int*)(ecp + E);           // [N]
    int*   row_ptr = cnt + N;                   // [N+1]
    int*   cursor  = row_ptr + N + 1;           // [N]
    int*   partial = cursor + N;                // [SCAN_NB]

    float* out_p    = (float*)d_out;            // [B]
    float* hidden_p = out_p + B;                // [B, 512]

    // ---- CSR build
    hipMemsetAsync(cnt, 0, (size_t)N * sizeof(int), stream);
    k_count<<<(E + 255) / 256, 256, 0, stream>>>(dstv, cnt, E);
    const int C = (N + SCAN_NB - 1) / SCAN_NB;
    k_scan_part<<<SCAN_NB, 256, 0, stream>>>(cnt, row_ptr, partial, N, C);
    k_scan_off<<<1, 256, 0, stream>>>(partial);
    k_scan_add<<<(N + 1 + 255) / 256, 256, 0, stream>>>(row_ptr, cursor, partial,
                                                        cnt, dinv, N, C, E);
    k_fill<<<(E + 255) / 256, 256, 0, stream>>>(srcv, dstv, dinv, cursor, ecp, E);

    // x -> f16 (+ zero layer-0 stats); all weights in one dispatch
    k_cast<<<(N * 64 / 4 + 255) / 256, 256, 0, stream>>>(x, xh, N * 64 / 4, sums, sumsq);
    k_prep_w_all<<<(16384 + 3 * 65536 + 255) / 256, 256, 0, stream>>>(
        Wl[0], Wl[1], Wl[2], Wl[3], Wt0, Wt1, Wt2, Wt3);

    const dim3 gemm_grid((N + 127) / 128, 2);
    const int nd4 = N * D / 4;
    const float Ninv = 1.0f / (float)N;
    f16* Wts[4] = {Wt0, Wt1, Wt2, Wt3};

    // ---- layer 0: quad-gather agg(X) -> GEMM(+stats) -> BN+tanh
    k_gather64<<<2048, 256, 0, stream>>>(row_ptr, ecp, xh, dinv, aggx, N);
    k_gemm<<<gemm_grid, 256, 0, stream>>>(aggx, Wt0, hw_h, N, 64,
                                          sums, sumsq, nullptr, nullptr);
    k_bn_tanh_h<<<(nd4 + 255) / 256, 256, 0, stream>>>(
        hw_h, sums, sumsq, gl[0], bel[0], Ninv, hh, nd4);

    // ---- layers 1-3: GEMM(zeroes stats) -> gather(+stats) -> BN+tanh (layer 3 BN fused into pool)
    for (int l = 1; l < 4; ++l) {
        k_gemm<<<gemm_grid, 256, 0, stream>>>(hh, Wts[l], hw_h, N, 256,
                                              nullptr, nullptr, sums, sumsq);
        k_gather<<<2048, 256, 0, stream>>>(row_ptr, ecp, hw_h, dinv,
                                           agg_h, sums, sumsq, N);
        if (l < 3) {
            k_bn_tanh_h<<<(nd4 + 255) / 256, 256, 0, stream>>>(
                agg_h, sums, sumsq, gl[l], bel[l], Ninv, hh, nd4);
        }
    }

    k_pool<<<B, 256, 0, stream>>>(agg_h, sums, sumsq, gl[3], bel[3], Ninv,
                                  batch, Wout, bout, out_p, hidden_p, N);
}